// Round 1
// baseline (435.323 us; speedup 1.0000x reference)
//
#include <hip/hip_runtime.h>
#include <math.h>

#define D 128
#define HQ 2        // node halves (was quarters: halves edge re-reads)
#define BB 64       // scan chunks per (g,h): grid = 2*HQ*BB = 256 blocks

// ---------------------------------------------------------------------------
// Collapsed linear GCN (math unchanged):
//   u0 = 1/N,  u_{k+1}[s] = sum_{e: src_e=s} inv_deg[dst_e] * u_k[dst_e]
//   mean(h3) = r@W0W1W2 + s2*(b0@W1W2) + s1*(b1@W2) + b2,  r = u3^T feat
// R9-R11 FAILED (fusion): kernel boundaries are the only cheap cross-XCD
// coherence. R13 (this round):
//   - deg via GLOBAL fp32 atomics (+1.0 is exact & order-independent):
//     kills deg-scan (76.8 MB) + reduce_inv rep readback (25.6 MB).
//     Also a live probe of device-scope scattered-atomic throughput: if
//     deg_kernel <= ~15us, convert prop scatters to atomics next round.
//   - prop scans HQ=2 (100 KB LDS, 1 blk/CU, 16 waves/CU): edge reads
//     halve per pass (102.4 -> 51.2 MB).
// ---------------------------------------------------------------------------

__global__ __launch_bounds__(256) void zero_kernel(float* __restrict__ buf, int n4) {
    float4* b4 = (float4*)buf;
    const float4 z = make_float4(0.f, 0.f, 0.f, 0.f);
    const int stride = gridDim.x * 256;
    for (int i = blockIdx.x * 256 + threadIdx.x; i < n4; i += stride) b4[i] = z;
}

// degree via global atomics: exact (integer-valued fp32 adds), order-free.
__global__ __launch_bounds__(256) void deg_kernel(
        const int* __restrict__ dst_p, const int* __restrict__ dst_s,
        float* __restrict__ deg, int E, int N) {
    const int g = blockIdx.y;
    const int* d = g ? dst_s : dst_p;
    float* dg = deg + (size_t)g * N;
    const int stride = gridDim.x * 256;
    const int E4 = E >> 2;
    for (int i = blockIdx.x * 256 + threadIdx.x; i < E4; i += stride) {
        int4 v = ((const int4*)d)[i];
        atomicAdd(&dg[v.x], 1.0f);
        atomicAdd(&dg[v.y], 1.0f);
        atomicAdd(&dg[v.z], 1.0f);
        atomicAdd(&dg[v.w], 1.0f);
    }
    if (blockIdx.x == 0 && blockIdx.y == 0 && (int)threadIdx.x < (E & 3)) {
        atomicAdd(&deg[0 * (size_t)N + dst_p[(E & ~3) + threadIdx.x]], 1.0f);
        atomicAdd(&deg[1 * (size_t)N + dst_s[(E & ~3) + threadIdx.x]], 1.0f);
    }
}

__global__ __launch_bounds__(256) void inv_kernel(
        const float* __restrict__ deg, float* __restrict__ inv, int n) {
    int i = blockIdx.x * 256 + threadIdx.x;
    if (i < n) inv[i] = 1.0f / fmaxf(deg[i], 1.0f);   // precise div, matches ref
}

// prop scatter pass: rep[g][h][b][HN] partial sums of w[g*N+dst[e]]*scale
// accumulated at src[e] (LDS bins, deterministic enough; absmax was 0.0).
__global__ __launch_bounds__(1024, 4) void scan_scatter(
        const int* __restrict__ tgt_p, const int* __restrict__ oth_p,
        const int* __restrict__ tgt_s, const int* __restrict__ oth_s,
        const float* __restrict__ w, float* __restrict__ rep,
        int E, int N, int HN, float scale) {
    const int b = blockIdx.x, h = blockIdx.y, g = blockIdx.z;
    const int* tgt = g ? tgt_s : tgt_p;
    const int* oth = g ? oth_s : oth_p;
    const float* wg = w + (size_t)g * N;

    extern __shared__ float lds[];  // HN floats (HN % 4 == 0), 100 KB
    {
        float4 z = make_float4(0.f, 0.f, 0.f, 0.f);
        float4* l4 = (float4*)lds;
        for (int i = threadIdx.x; i < HN / 4; i += 1024) l4[i] = z;
    }
    __syncthreads();

    const int lo = h * HN;
    const int hi = min(lo + HN, N);
    const unsigned span = (unsigned)(hi - lo);
    int C = (E + BB - 1) / BB;
    C = (C + 7) & ~7;
    const int e0 = b * C;
    const int e1 = min(e0 + C, E);

    for (int e = e0 + (int)threadIdx.x * 8; e < e1; e += 1024 * 8) {
        if (e + 8 <= e1) {
            int4 ta = *(const int4*)(tgt + e);
            int4 tb = *(const int4*)(tgt + e + 4);
            int idx[8] = {ta.x, ta.y, ta.z, ta.w, tb.x, tb.y, tb.z, tb.w};
            bool hit[8];
            #pragma unroll
            for (int k = 0; k < 8; ++k) hit[k] = (unsigned)(idx[k] - lo) < span;
            int4 oa = *(const int4*)(oth + e);
            int4 ob = *(const int4*)(oth + e + 4);
            int od[8] = {oa.x, oa.y, oa.z, oa.w, ob.x, ob.y, ob.z, ob.w};
            float val[8];
            #pragma unroll
            for (int k = 0; k < 8; ++k) val[k] = hit[k] ? wg[od[k]] : 0.f;
            #pragma unroll
            for (int k = 0; k < 8; ++k)
                if (hit[k]) atomicAdd(&lds[idx[k] - lo], val[k] * scale);
        } else {
            for (int e2 = e; e2 < e1; ++e2) {
                int t = tgt[e2];
                if ((unsigned)(t - lo) < span)
                    atomicAdd(&lds[t - lo], wg[oth[e2]] * scale);
            }
        }
    }
    __syncthreads();

    float* dst = rep + (((size_t)g * HQ + h) * BB + b) * HN;
    float4* d4 = (float4*)dst;
    const float4* l4 = (const float4*)lds;
    for (int i = threadIdx.x; i < HN / 4; i += 1024) d4[i] = l4[i];
}

// u = sum_b rep; optional out_u, out_w = u*inv; optional per-graph sums
__global__ __launch_bounds__(256) void reduce_u(
        const float* __restrict__ rep, const float* __restrict__ inv,
        float* __restrict__ out_u, float* __restrict__ out_w,
        float* __restrict__ sums, int s_idx, int N, int HN) {
    const int lane = threadIdx.x & 63;
    const int s = threadIdx.x >> 6;
    const int i = (blockIdx.x * 64 + lane) * 4;
    const int bps = BB >> 2;                  // 16
    float4 u = make_float4(0.f, 0.f, 0.f, 0.f);
    if (i < 2 * N) {
        int g = (i < N) ? 0 : 1;
        int n = i - g * N;
        int h = n / HN, l = n - h * HN;
        const float* base = rep + (((size_t)g * HQ + h) * BB + (size_t)s * bps) * HN + l;
        #pragma unroll 16
        for (int b = 0; b < bps; b++) {
            float4 v = *(const float4*)(base + (size_t)b * HN);
            u.x += v.x; u.y += v.y; u.z += v.z; u.w += v.w;
        }
    }
    __shared__ float4 sm[256];
    __shared__ float s0[64], s1[64];
    sm[threadIdx.x] = u;
    __syncthreads();
    if (s == 0) {
        float tp = 0.f, ts = 0.f;
        if (i < 2 * N) {
            float4 a = sm[lane], b4 = sm[64 + lane], c = sm[128 + lane], d = sm[192 + lane];
            float4 uu;
            uu.x = a.x + b4.x + c.x + d.x;
            uu.y = a.y + b4.y + c.y + d.y;
            uu.z = a.z + b4.z + c.z + d.z;
            uu.w = a.w + b4.w + c.w + d.w;
            if (out_u) *(float4*)(out_u + i) = uu;
            if (out_w) {
                float4 iv = *(const float4*)(inv + i);
                *(float4*)(out_w + i) =
                    make_float4(uu.x * iv.x, uu.y * iv.y, uu.z * iv.z, uu.w * iv.w);
            }
            float t = uu.x + uu.y + uu.z + uu.w;
            if (i < N) tp = t; else ts = t;
        }
        s0[lane] = tp; s1[lane] = ts;
    }
    __syncthreads();
    if (sums) {
        for (int st = 32; st > 0; st >>= 1) {
            if ((int)threadIdx.x < st) {
                s0[threadIdx.x] += s0[threadIdx.x + st];
                s1[threadIdx.x] += s1[threadIdx.x + st];
            }
            __syncthreads();
        }
        if (threadIdx.x == 0) {
            if (s0[0] != 0.f) atomicAdd(&sums[0 * 2 + s_idx], s0[0]);
            if (s1[0] != 0.f) atomicAdd(&sums[1 * 2 + s_idx], s1[0]);
        }
    }
}

// featsum: per-block partial of u3^T feat, atomically accumulated into
// fpart2[g][blockIdx.x & 15][c]  (fpart2 pre-zeroed by zero_kernel).
__global__ __launch_bounds__(256) void featsum_kernel(
        const float* __restrict__ feat_p, const float* __restrict__ feat_s,
        const float* __restrict__ u3, float* __restrict__ fpart2,
        int N, int rpb) {
    const int g = blockIdx.y;
    const float* feat = g ? feat_s : feat_p;
    const float* u = u3 + (size_t)g * N;
    const int col4 = threadIdx.x & 31;
    const int rgrp = threadIdx.x >> 5;   // 0..7
    const int r0 = blockIdx.x * rpb;
    const int r1 = min(r0 + rpb, N);

    const float4* f4 = (const float4*)feat;
    float4 acc = make_float4(0.f, 0.f, 0.f, 0.f);
    for (int n = r0 + rgrp * 4; n + 3 < r1; n += 32) {
        float4 uu = *(const float4*)(u + n);
        float4 v0 = f4[(size_t)n * 32 + col4];
        float4 v1 = f4[(size_t)(n + 1) * 32 + col4];
        float4 v2 = f4[(size_t)(n + 2) * 32 + col4];
        float4 v3 = f4[(size_t)(n + 3) * 32 + col4];
        acc.x += uu.x * v0.x + uu.y * v1.x + uu.z * v2.x + uu.w * v3.x;
        acc.y += uu.x * v0.y + uu.y * v1.y + uu.z * v2.y + uu.w * v3.y;
        acc.z += uu.x * v0.z + uu.y * v1.z + uu.z * v2.z + uu.w * v3.z;
        acc.w += uu.x * v0.w + uu.y * v1.w + uu.z * v2.w + uu.w * v3.w;
    }
    __shared__ float4 smem[256];
    smem[threadIdx.x] = acc;
    __syncthreads();
    if (rgrp == 0) {
        float4 t = smem[col4];
        #pragma unroll
        for (int k = 1; k < 8; k++) {
            float4 o = smem[k * 32 + col4];
            t.x += o.x; t.y += o.y; t.z += o.z; t.w += o.w;
        }
        float* dst = fpart2 + ((size_t)g * 16 + (blockIdx.x & 15)) * 128 + col4 * 4;
        atomicAdd(dst + 0, t.x);
        atomicAdd(dst + 1, t.y);
        atomicAdd(dst + 2, t.z);
        atomicAdd(dst + 3, t.w);
    }
}

// 512 threads: split-K matvecs. j = tid&127, h = tid>>7.
__global__ __launch_bounds__(512) void final_kernel(
        const float* __restrict__ fpart2,
        const float* __restrict__ sums,
        const float* __restrict__ W0, const float* __restrict__ b0,
        const float* __restrict__ W1, const float* __restrict__ b1,
        const float* __restrict__ W2, const float* __restrict__ b2,
        const float* __restrict__ Wr, const float* __restrict__ br,
        const float* __restrict__ Wm1, const float* __restrict__ bm1,
        const float* __restrict__ Wm2, const float* __restrict__ bm2,
        float* __restrict__ out) {
    __shared__ float x[128];
    __shared__ float part[4][128];
    __shared__ float rvec[256];
    __shared__ float Avec[128], Bvec[128];
    __shared__ float gv[256];
    const int tid = threadIdx.x;
    const int j = tid & 127;
    const int h = tid >> 7;

    auto mv128 = [&](const float* __restrict__ W, float* __restrict__ buf) {
        float p = 0.f;
        const float* Wp = W + (size_t)(h * 32) * 128 + j;
        #pragma unroll
        for (int i = 0; i < 32; ++i) p += buf[h * 32 + i] * Wp[(size_t)i * 128];
        part[h][j] = p;
        __syncthreads();
        if (h == 0) buf[j] = part[0][j] + part[1][j] + part[2][j] + part[3][j];
        __syncthreads();
    };

    if (tid < 256) {
        int g = tid >> 7;
        const float* fp = fpart2 + (size_t)g * 2048 + (tid & 127);
        float rv = 0.f;
        #pragma unroll
        for (int b = 0; b < 16; ++b) rv += fp[(size_t)b * 128];
        rvec[tid] = rv;
    }
    __syncthreads();

    if (tid < 128) x[tid] = b0[tid];
    __syncthreads();
    mv128(W1, x);
    mv128(W2, x);
    if (tid < 128) Avec[tid] = x[tid];
    __syncthreads();
    if (tid < 128) x[tid] = b1[tid];
    __syncthreads();
    mv128(W2, x);
    if (tid < 128) Bvec[tid] = x[tid];
    __syncthreads();

    for (int g = 0; g < 2; ++g) {
        const float s1 = sums[g * 2 + 0];
        const float s2 = sums[g * 2 + 1];
        if (tid < 128) x[tid] = rvec[g * 128 + tid];
        __syncthreads();
        mv128(W0, x);
        mv128(W1, x);
        mv128(W2, x);
        if (tid < 128) x[tid] += s2 * Avec[tid] + s1 * Bvec[tid] + b2[tid];
        __syncthreads();
        mv128(Wr, x);
        if (tid < 128) gv[g * 128 + tid] = 1.0f / (1.0f + expf(-(x[tid] + br[tid])));
        __syncthreads();
    }

    {
        float p = 0.f;
        const float* Wp = Wm1 + (size_t)(h * 64) * 128 + j;
        #pragma unroll
        for (int i = 0; i < 64; ++i) p += gv[h * 64 + i] * Wp[(size_t)i * 128];
        part[h][j] = p;
        __syncthreads();
        if (h == 0)
            part[0][j] = (part[0][j] + part[1][j] + part[2][j] + part[3][j] + bm1[j]) * Wm2[j];
        __syncthreads();
        if (tid < 64) part[0][tid] += part[0][tid + 64];
        __syncthreads();
        if (tid < 32) part[0][tid] += part[0][tid + 32];
        __syncthreads();
        if (tid < 16) part[0][tid] += part[0][tid + 16];
        __syncthreads();
        if (tid < 8) part[0][tid] += part[0][tid + 8];
        __syncthreads();
        if (tid < 4) part[0][tid] += part[0][tid + 4];
        __syncthreads();
        if (tid < 2) part[0][tid] += part[0][tid + 2];
        __syncthreads();
        if (tid == 0) out[0] = 1.0f / (1.0f + expf(-(part[0][0] + part[0][1] + bm2[0])));
    }
}

extern "C" void kernel_launch(void* const* d_in, const int* in_sizes, int n_in,
                              void* d_out, int out_size, void* d_ws, size_t ws_size,
                              hipStream_t stream) {
    const float* feat_p = (const float*)d_in[0];
    const int*   src_p  = (const int*)d_in[1];
    const int*   dst_p  = (const int*)d_in[2];
    const float* feat_s = (const float*)d_in[3];
    const int*   src_s  = (const int*)d_in[4];
    const int*   dst_s  = (const int*)d_in[5];
    const float* W0 = (const float*)d_in[6];
    const float* b0 = (const float*)d_in[7];
    const float* W1 = (const float*)d_in[8];
    const float* b1 = (const float*)d_in[9];
    const float* W2 = (const float*)d_in[10];
    const float* b2 = (const float*)d_in[11];
    const float* Wr = (const float*)d_in[12];
    const float* br = (const float*)d_in[13];
    const float* Wm1 = (const float*)d_in[14];
    const float* bm1 = (const float*)d_in[15];
    const float* Wm2 = (const float*)d_in[16];
    const float* bm2 = (const float*)d_in[17];
    float* out = (float*)d_out;

    const int N = in_sizes[0] / D;   // 50000
    const int E = in_sizes[1];       // 1600000
    const int N2 = 2 * N;

    int HN = (N + HQ - 1) / HQ;
    HN = (HN + 3) & ~3;              // 25000
    const int FB = 256;              // featsum blocks per graph
    const int rpb = (((N + FB - 1) / FB) + 3) & ~3;   // 196

    // ws (floats): sums[16] | fpart2[2*16*128] | deg[2N] | inv[2N] | w1[2N] |
    //              w2[2N] | u3[2N] | rep[2*HQ*BB*HN]
    float* ws     = (float*)d_ws;
    float* sums   = ws;
    float* fpart2 = ws + 16;
    float* deg    = fpart2 + 2 * 16 * 128;
    float* inv    = deg + N2;
    float* w1     = inv + N2;
    float* w2     = w1 + N2;
    float* u3     = w2 + N2;
    float* rep    = u3 + N2;

    const dim3 sgrid(BB, HQ, 2);     // 256 blocks x 1024 thr, 1/CU, 16 waves/CU
    const size_t lds_bytes = (size_t)HN * sizeof(float);  // 100 KB
    const int gQ = (N2 / 4 + 63) / 64;   // 391 reduce blocks
    const float u0 = 1.0f / (float)N;
    const int zc4 = (16 + 2 * 16 * 128 + N2) / 4;   // sums+fpart2+deg, /4

    static bool attr_done = false;
    if (!attr_done) {
        (void)hipFuncSetAttribute(reinterpret_cast<const void*>(scan_scatter),
                                  hipFuncAttributeMaxDynamicSharedMemorySize,
                                  (int)lds_bytes);
        attr_done = true;
    }

    zero_kernel<<<128, 256, 0, stream>>>(ws, zc4);
    deg_kernel<<<dim3(512, 2), 256, 0, stream>>>(dst_p, dst_s, deg, E, N);
    inv_kernel<<<(N2 + 255) / 256, 256, 0, stream>>>(deg, inv, N2);

    scan_scatter<<<sgrid, 1024, lds_bytes, stream>>>(src_p, dst_p, src_s, dst_s,
                                                     inv, rep, E, N, HN, u0);
    reduce_u<<<gQ, 256, 0, stream>>>(rep, inv, nullptr, w1, sums, 0, N, HN);

    scan_scatter<<<sgrid, 1024, lds_bytes, stream>>>(src_p, dst_p, src_s, dst_s,
                                                     w1, rep, E, N, HN, 1.0f);
    reduce_u<<<gQ, 256, 0, stream>>>(rep, inv, nullptr, w2, sums, 1, N, HN);

    scan_scatter<<<sgrid, 1024, lds_bytes, stream>>>(src_p, dst_p, src_s, dst_s,
                                                     w2, rep, E, N, HN, 1.0f);
    reduce_u<<<gQ, 256, 0, stream>>>(rep, inv, u3, nullptr, nullptr, 0, N, HN);

    featsum_kernel<<<dim3(FB, 2), 256, 0, stream>>>(feat_p, feat_s, u3, fpart2, N, rpb);

    final_kernel<<<1, 512, 0, stream>>>(fpart2, sums, W0, b0, W1, b1, W2, b2,
                                        Wr, br, Wm1, bm1, Wm2, bm2, out);
}

// Round 2
// 351.891 us; speedup vs baseline: 1.2371x; 1.2371x over previous
//
#include <hip/hip_runtime.h>
#include <math.h>

#define D 128
#define HQ 4        // node quarters: 50 KB LDS, 2 blocks/CU (R13 lesson: HQ=2 = 1 blk/CU regressed)
#define BB 64       // scan chunks per (g,h): grid = 2*HQ*BB = 512 blocks
#define CAP 425984  // per-bucket edge capacity: E/4=400000 + 26K slack (~47 sigma), mult of 8

// ---------------------------------------------------------------------------
// Collapsed linear GCN (math unchanged):
//   u0 = 1/N,  u_{k+1}[s] = sum_{e: src_e=s} inv_deg[dst_e] * u_k[dst_e]
//   mean(h3) = r@W0W1W2 + s2*(b0@W1W2) + s1*(b1@W2) + b2,  r = u3^T feat
// MEASURED LESSONS:
//   R9-R11: kernel boundaries are the only cheap cross-XCD coherence.
//   R13: scattered global fp32 atomics = 171us for 3.2M adds (632 GB/s,
//        WRITE_SIZE 99.6MB = per-atomic line RMW). NEVER scatter-atomic at
//        E scale. Also HQ=2 (100KB LDS, 1 blk/CU) halved scan occupancy.
// R14 (this round): one-shot edge binning kills the HQ x edge re-read:
//   - bin_kernel partitions edges by src-quarter (prop) AND dst-quarter
//     (deg), each edge packed into ONE int: (local_node<<17)|dst.
//     Cursor reservation = wave-ballot aggregate + per-block LDS counts ->
//     ~16K global atomics on 16 addresses (R13 lesson applied).
//   - prop scan edge reads: 102.4 MB -> 12.8 MB per pass (8x).
//   - deg scan: 51.2 -> 12.8 MB.
// ---------------------------------------------------------------------------

__global__ __launch_bounds__(256) void zero_kernel(float* __restrict__ buf, int n4) {
    float4* b4 = (float4*)buf;
    const float4 z = make_float4(0.f, 0.f, 0.f, 0.f);
    const int stride = gridDim.x * 256;
    for (int i = blockIdx.x * 256 + threadIdx.x; i < n4; i += stride) b4[i] = z;
}

// Partition edges into 4 src-quarter buckets (payload (src_local<<17)|dst)
// and 4 dst-quarter buckets (payload dst_local<<17). Wave-ballot aggregated
// reservation: LDS counters per block-chunk, 8 global atomicAdds per chunk.
__global__ __launch_bounds__(512) void bin_kernel(
        const int* __restrict__ src_p, const int* __restrict__ dst_p,
        const int* __restrict__ src_s, const int* __restrict__ dst_s,
        int* __restrict__ sbins, int* __restrict__ dbins,
        unsigned* __restrict__ cur,   // [0..7] src cursors, [8..15] dst cursors
        int E, int HN) {
    const int g = blockIdx.y;
    const int* src = g ? src_s : src_p;
    const int* dst = g ? dst_s : dst_p;
    int* sb = sbins + (size_t)g * 4 * CAP;
    int* db = dbins + (size_t)g * 4 * CAP;
    unsigned* scur = cur + g * 4;
    unsigned* dcur = cur + 8 + g * 4;

    const int tid = threadIdx.x;
    const int lane = tid & 63;
    const unsigned long long lmlt = (1ull << lane) - 1ull;
    const int HN2 = 2 * HN, HN3 = 3 * HN;

    __shared__ unsigned cnt[8];   // 0..3 src-bucket counts, 4..7 dst-bucket
    __shared__ unsigned base[8];

    const int per = ((E + (int)gridDim.x - 1) / (int)gridDim.x + 7) & ~7;
    const int e0 = blockIdx.x * per;
    const int e1 = min(e0 + per, E);

    for (int c0 = e0; c0 < e1; c0 += 512 * 8) {   // 4096-edge chunks
        int myS[8], myD[8], qs[8], qd[8];
        const int eb = c0 + tid * 8;
        if (eb + 8 <= e1) {
            int4 a = *(const int4*)(src + eb); int4 b = *(const int4*)(src + eb + 4);
            int4 c = *(const int4*)(dst + eb); int4 d = *(const int4*)(dst + eb + 4);
            myS[0]=a.x; myS[1]=a.y; myS[2]=a.z; myS[3]=a.w;
            myS[4]=b.x; myS[5]=b.y; myS[6]=b.z; myS[7]=b.w;
            myD[0]=c.x; myD[1]=c.y; myD[2]=c.z; myD[3]=c.w;
            myD[4]=d.x; myD[5]=d.y; myD[6]=d.z; myD[7]=d.w;
        } else {
            #pragma unroll
            for (int k = 0; k < 8; ++k) {
                int e = eb + k;
                myS[k] = (e < e1) ? src[e] : -1;
                myD[k] = (e < e1) ? dst[e] : -1;
            }
        }
        #pragma unroll
        for (int k = 0; k < 8; ++k) {
            qs[k] = (myS[k] < 0) ? -1
                  : ((myS[k] >= HN2) ? (myS[k] >= HN3 ? 3 : 2)
                                     : (myS[k] >= HN ? 1 : 0));
            qd[k] = (myD[k] < 0) ? -1
                  : ((myD[k] >= HN2) ? (myD[k] >= HN3 ? 3 : 2)
                                     : (myD[k] >= HN ? 1 : 0));
        }

        if (tid < 8) cnt[tid] = 0;
        __syncthreads();

        unsigned sr[8], dr[8];
        #pragma unroll
        for (int k = 0; k < 8; ++k) {
            sr[k] = 0; dr[k] = 0;
            #pragma unroll
            for (int b = 0; b < 4; ++b) {
                unsigned long long ms = __ballot(qs[k] == b);
                if (ms) {
                    int ld = (int)__ffsll((long long)ms) - 1;
                    int wb = 0;
                    if (lane == ld) wb = (int)atomicAdd(&cnt[b], (unsigned)__popcll(ms));
                    wb = __shfl(wb, ld);
                    if (qs[k] == b) sr[k] = (unsigned)wb + (unsigned)__popcll(ms & lmlt);
                }
                unsigned long long md = __ballot(qd[k] == b);
                if (md) {
                    int ld2 = (int)__ffsll((long long)md) - 1;
                    int wb2 = 0;
                    if (lane == ld2) wb2 = (int)atomicAdd(&cnt[4 + b], (unsigned)__popcll(md));
                    wb2 = __shfl(wb2, ld2);
                    if (qd[k] == b) dr[k] = (unsigned)wb2 + (unsigned)__popcll(md & lmlt);
                }
            }
        }
        __syncthreads();
        if (tid < 4)      base[tid] = atomicAdd(&scur[tid], cnt[tid]);
        else if (tid < 8) base[tid] = atomicAdd(&dcur[tid - 4], cnt[tid]);
        __syncthreads();

        #pragma unroll
        for (int k = 0; k < 8; ++k) {
            if (qs[k] >= 0) {
                unsigned p = base[qs[k]] + sr[k];
                if (p < (unsigned)CAP)
                    sb[(size_t)qs[k] * CAP + p] = ((myS[k] - qs[k] * HN) << 17) | myD[k];
            }
            if (qd[k] >= 0) {
                unsigned p = base[4 + qd[k]] + dr[k];
                if (p < (unsigned)CAP)
                    db[(size_t)qd[k] * CAP + p] = (myD[k] - qd[k] * HN) << 17;
            }
        }
        __syncthreads();
    }
}

// Scan over one bucket: LDS-binned scatter, rep[g][h][b][HN] partials.
//   deg pass:  bins=dbins, w=null -> +1 per edge
//   prop pass: bins=sbins, w     -> + w[g*N + (v&0x1FFFF)] * scale at (v>>17)
__global__ __launch_bounds__(1024, 8) void scan_binned(
        const int* __restrict__ bins, const unsigned* __restrict__ bcnt,
        const float* __restrict__ w, float* __restrict__ rep,
        int N, int HN, float scale) {
    const int b = blockIdx.x, h = blockIdx.y, g = blockIdx.z;
    const int* bin = bins + (size_t)(g * HQ + h) * CAP;
    const int n = (int)bcnt[g * HQ + h];
    const float* wg = w ? (w + (size_t)g * N) : nullptr;

    extern __shared__ float lds[];  // HN floats, 50 KB
    {
        float4 z = make_float4(0.f, 0.f, 0.f, 0.f);
        float4* l4 = (float4*)lds;
        for (int i = threadIdx.x; i < HN / 4; i += 1024) l4[i] = z;
    }
    __syncthreads();

    int C = (n + BB - 1) / BB;
    C = (C + 7) & ~7;
    const int e0 = b * C;
    const int e1 = min(e0 + C, n);

    for (int e = e0 + (int)threadIdx.x * 8; e < e1; e += 1024 * 8) {
        if (e + 8 <= e1) {
            int4 a = *(const int4*)(bin + e);
            int4 bb = *(const int4*)(bin + e + 4);
            int v[8] = {a.x, a.y, a.z, a.w, bb.x, bb.y, bb.z, bb.w};
            float val[8];
            #pragma unroll
            for (int k = 0; k < 8; ++k)
                val[k] = wg ? wg[v[k] & 0x1FFFF] * scale : 1.0f;
            #pragma unroll
            for (int k = 0; k < 8; ++k)
                atomicAdd(&lds[((unsigned)v[k]) >> 17], val[k]);
        } else {
            for (int e2 = e; e2 < e1; ++e2) {
                int v = bin[e2];
                float val = wg ? wg[v & 0x1FFFF] * scale : 1.0f;
                atomicAdd(&lds[((unsigned)v) >> 17], val);
            }
        }
    }
    __syncthreads();

    float* dst = rep + (((size_t)g * HQ + h) * BB + b) * HN;
    float4* d4 = (float4*)dst;
    const float4* l4 = (const float4*)lds;
    for (int i = threadIdx.x; i < HN / 4; i += 1024) d4[i] = l4[i];
}

// 256 threads = 64 quads x 4 B-slices; each thread sums B/4 = 16 partials.
__global__ __launch_bounds__(256) void reduce_inv(
        const float* __restrict__ rep, float* __restrict__ inv,
        int N, int HN) {
    const int lane = threadIdx.x & 63;
    const int s = threadIdx.x >> 6;
    const int i = (blockIdx.x * 64 + lane) * 4;
    const int bps = BB >> 2;                  // 16
    float4 u = make_float4(0.f, 0.f, 0.f, 0.f);
    if (i < 2 * N) {
        int g = (i < N) ? 0 : 1;
        int n = i - g * N;
        int h = n / HN, l = n - h * HN;
        const float* base = rep + (((size_t)g * HQ + h) * BB + (size_t)s * bps) * HN + l;
        #pragma unroll 16
        for (int b = 0; b < bps; b++) {
            float4 v = *(const float4*)(base + (size_t)b * HN);
            u.x += v.x; u.y += v.y; u.z += v.z; u.w += v.w;
        }
    }
    __shared__ float4 sm[256];
    sm[threadIdx.x] = u;
    __syncthreads();
    if (s == 0 && i < 2 * N) {
        float4 a = sm[lane], b4 = sm[64 + lane], c = sm[128 + lane], d = sm[192 + lane];
        float4 r;
        r.x = 1.0f / fmaxf(a.x + b4.x + c.x + d.x, 1.0f);
        r.y = 1.0f / fmaxf(a.y + b4.y + c.y + d.y, 1.0f);
        r.z = 1.0f / fmaxf(a.z + b4.z + c.z + d.z, 1.0f);
        r.w = 1.0f / fmaxf(a.w + b4.w + c.w + d.w, 1.0f);
        *(float4*)(inv + i) = r;
    }
}

// u = sum_b rep; optional out_u, out_w = u*inv; optional per-graph sums
__global__ __launch_bounds__(256) void reduce_u(
        const float* __restrict__ rep, const float* __restrict__ inv,
        float* __restrict__ out_u, float* __restrict__ out_w,
        float* __restrict__ sums, int s_idx, int N, int HN) {
    const int lane = threadIdx.x & 63;
    const int s = threadIdx.x >> 6;
    const int i = (blockIdx.x * 64 + lane) * 4;
    const int bps = BB >> 2;                  // 16
    float4 u = make_float4(0.f, 0.f, 0.f, 0.f);
    if (i < 2 * N) {
        int g = (i < N) ? 0 : 1;
        int n = i - g * N;
        int h = n / HN, l = n - h * HN;
        const float* base = rep + (((size_t)g * HQ + h) * BB + (size_t)s * bps) * HN + l;
        #pragma unroll 16
        for (int b = 0; b < bps; b++) {
            float4 v = *(const float4*)(base + (size_t)b * HN);
            u.x += v.x; u.y += v.y; u.z += v.z; u.w += v.w;
        }
    }
    __shared__ float4 sm[256];
    __shared__ float s0[64], s1[64];
    sm[threadIdx.x] = u;
    __syncthreads();
    if (s == 0) {
        float tp = 0.f, ts = 0.f;
        if (i < 2 * N) {
            float4 a = sm[lane], b4 = sm[64 + lane], c = sm[128 + lane], d = sm[192 + lane];
            float4 uu;
            uu.x = a.x + b4.x + c.x + d.x;
            uu.y = a.y + b4.y + c.y + d.y;
            uu.z = a.z + b4.z + c.z + d.z;
            uu.w = a.w + b4.w + c.w + d.w;
            if (out_u) *(float4*)(out_u + i) = uu;
            if (out_w) {
                float4 iv = *(const float4*)(inv + i);
                *(float4*)(out_w + i) =
                    make_float4(uu.x * iv.x, uu.y * iv.y, uu.z * iv.z, uu.w * iv.w);
            }
            float t = uu.x + uu.y + uu.z + uu.w;
            if (i < N) tp = t; else ts = t;
        }
        s0[lane] = tp; s1[lane] = ts;
    }
    __syncthreads();
    if (sums) {
        for (int st = 32; st > 0; st >>= 1) {
            if ((int)threadIdx.x < st) {
                s0[threadIdx.x] += s0[threadIdx.x + st];
                s1[threadIdx.x] += s1[threadIdx.x + st];
            }
            __syncthreads();
        }
        if (threadIdx.x == 0) {
            if (s0[0] != 0.f) atomicAdd(&sums[0 * 2 + s_idx], s0[0]);
            if (s1[0] != 0.f) atomicAdd(&sums[1 * 2 + s_idx], s1[0]);
        }
    }
}

// featsum: per-block partial of u3^T feat, atomically accumulated into
// fpart2[g][blockIdx.x & 15][c]  (fpart2 pre-zeroed by zero_kernel).
__global__ __launch_bounds__(256) void featsum_kernel(
        const float* __restrict__ feat_p, const float* __restrict__ feat_s,
        const float* __restrict__ u3, float* __restrict__ fpart2,
        int N, int rpb) {
    const int g = blockIdx.y;
    const float* feat = g ? feat_s : feat_p;
    const float* u = u3 + (size_t)g * N;
    const int col4 = threadIdx.x & 31;
    const int rgrp = threadIdx.x >> 5;   // 0..7
    const int r0 = blockIdx.x * rpb;
    const int r1 = min(r0 + rpb, N);

    const float4* f4 = (const float4*)feat;
    float4 acc = make_float4(0.f, 0.f, 0.f, 0.f);
    for (int n = r0 + rgrp * 4; n + 3 < r1; n += 32) {
        float4 uu = *(const float4*)(u + n);
        float4 v0 = f4[(size_t)n * 32 + col4];
        float4 v1 = f4[(size_t)(n + 1) * 32 + col4];
        float4 v2 = f4[(size_t)(n + 2) * 32 + col4];
        float4 v3 = f4[(size_t)(n + 3) * 32 + col4];
        acc.x += uu.x * v0.x + uu.y * v1.x + uu.z * v2.x + uu.w * v3.x;
        acc.y += uu.x * v0.y + uu.y * v1.y + uu.z * v2.y + uu.w * v3.y;
        acc.z += uu.x * v0.z + uu.y * v1.z + uu.z * v2.z + uu.w * v3.z;
        acc.w += uu.x * v0.w + uu.y * v1.w + uu.z * v2.w + uu.w * v3.w;
    }
    __shared__ float4 smem[256];
    smem[threadIdx.x] = acc;
    __syncthreads();
    if (rgrp == 0) {
        float4 t = smem[col4];
        #pragma unroll
        for (int k = 1; k < 8; k++) {
            float4 o = smem[k * 32 + col4];
            t.x += o.x; t.y += o.y; t.z += o.z; t.w += o.w;
        }
        float* dst = fpart2 + ((size_t)g * 16 + (blockIdx.x & 15)) * 128 + col4 * 4;
        atomicAdd(dst + 0, t.x);
        atomicAdd(dst + 1, t.y);
        atomicAdd(dst + 2, t.z);
        atomicAdd(dst + 3, t.w);
    }
}

// 512 threads: split-K matvecs. j = tid&127, h = tid>>7.
__global__ __launch_bounds__(512) void final_kernel(
        const float* __restrict__ fpart2,
        const float* __restrict__ sums,
        const float* __restrict__ W0, const float* __restrict__ b0,
        const float* __restrict__ W1, const float* __restrict__ b1,
        const float* __restrict__ W2, const float* __restrict__ b2,
        const float* __restrict__ Wr, const float* __restrict__ br,
        const float* __restrict__ Wm1, const float* __restrict__ bm1,
        const float* __restrict__ Wm2, const float* __restrict__ bm2,
        float* __restrict__ out) {
    __shared__ float x[128];
    __shared__ float part[4][128];
    __shared__ float rvec[256];
    __shared__ float Avec[128], Bvec[128];
    __shared__ float gv[256];
    const int tid = threadIdx.x;
    const int j = tid & 127;
    const int h = tid >> 7;

    auto mv128 = [&](const float* __restrict__ W, float* __restrict__ buf) {
        float p = 0.f;
        const float* Wp = W + (size_t)(h * 32) * 128 + j;
        #pragma unroll
        for (int i = 0; i < 32; ++i) p += buf[h * 32 + i] * Wp[(size_t)i * 128];
        part[h][j] = p;
        __syncthreads();
        if (h == 0) buf[j] = part[0][j] + part[1][j] + part[2][j] + part[3][j];
        __syncthreads();
    };

    if (tid < 256) {
        int g = tid >> 7;
        const float* fp = fpart2 + (size_t)g * 2048 + (tid & 127);
        float rv = 0.f;
        #pragma unroll
        for (int b = 0; b < 16; ++b) rv += fp[(size_t)b * 128];
        rvec[tid] = rv;
    }
    __syncthreads();

    if (tid < 128) x[tid] = b0[tid];
    __syncthreads();
    mv128(W1, x);
    mv128(W2, x);
    if (tid < 128) Avec[tid] = x[tid];
    __syncthreads();
    if (tid < 128) x[tid] = b1[tid];
    __syncthreads();
    mv128(W2, x);
    if (tid < 128) Bvec[tid] = x[tid];
    __syncthreads();

    for (int g = 0; g < 2; ++g) {
        const float s1 = sums[g * 2 + 0];
        const float s2 = sums[g * 2 + 1];
        if (tid < 128) x[tid] = rvec[g * 128 + tid];
        __syncthreads();
        mv128(W0, x);
        mv128(W1, x);
        mv128(W2, x);
        if (tid < 128) x[tid] += s2 * Avec[tid] + s1 * Bvec[tid] + b2[tid];
        __syncthreads();
        mv128(Wr, x);
        if (tid < 128) gv[g * 128 + tid] = 1.0f / (1.0f + expf(-(x[tid] + br[tid])));
        __syncthreads();
    }

    {
        float p = 0.f;
        const float* Wp = Wm1 + (size_t)(h * 64) * 128 + j;
        #pragma unroll
        for (int i = 0; i < 64; ++i) p += gv[h * 64 + i] * Wp[(size_t)i * 128];
        part[h][j] = p;
        __syncthreads();
        if (h == 0)
            part[0][j] = (part[0][j] + part[1][j] + part[2][j] + part[3][j] + bm1[j]) * Wm2[j];
        __syncthreads();
        if (tid < 64) part[0][tid] += part[0][tid + 64];
        __syncthreads();
        if (tid < 32) part[0][tid] += part[0][tid + 32];
        __syncthreads();
        if (tid < 16) part[0][tid] += part[0][tid + 16];
        __syncthreads();
        if (tid < 8) part[0][tid] += part[0][tid + 8];
        __syncthreads();
        if (tid < 4) part[0][tid] += part[0][tid + 4];
        __syncthreads();
        if (tid < 2) part[0][tid] += part[0][tid + 2];
        __syncthreads();
        if (tid == 0) out[0] = 1.0f / (1.0f + expf(-(part[0][0] + part[0][1] + bm2[0])));
    }
}

extern "C" void kernel_launch(void* const* d_in, const int* in_sizes, int n_in,
                              void* d_out, int out_size, void* d_ws, size_t ws_size,
                              hipStream_t stream) {
    const float* feat_p = (const float*)d_in[0];
    const int*   src_p  = (const int*)d_in[1];
    const int*   dst_p  = (const int*)d_in[2];
    const float* feat_s = (const float*)d_in[3];
    const int*   src_s  = (const int*)d_in[4];
    const int*   dst_s  = (const int*)d_in[5];
    const float* W0 = (const float*)d_in[6];
    const float* b0 = (const float*)d_in[7];
    const float* W1 = (const float*)d_in[8];
    const float* b1 = (const float*)d_in[9];
    const float* W2 = (const float*)d_in[10];
    const float* b2 = (const float*)d_in[11];
    const float* Wr = (const float*)d_in[12];
    const float* br = (const float*)d_in[13];
    const float* Wm1 = (const float*)d_in[14];
    const float* bm1 = (const float*)d_in[15];
    const float* Wm2 = (const float*)d_in[16];
    const float* bm2 = (const float*)d_in[17];
    float* out = (float*)d_out;

    const int N = in_sizes[0] / D;   // 50000
    const int E = in_sizes[1];       // 1600000
    const int N2 = 2 * N;

    int HN = (N + HQ - 1) / HQ;
    HN = (HN + 3) & ~3;              // 12500
    const int FB = 256;              // featsum blocks per graph
    const int rpb = (((N + FB - 1) / FB) + 3) & ~3;   // 196

    // ws (floats): cur[16u] | sums[16] | fpart2[2*16*128] | inv[2N] | w1[2N] |
    //              w2[2N] | u3[2N] | rep[2*HQ*BB*HN] | sbins[2*4*CAP int] |
    //              dbins[2*4*CAP int]   (~54.5 MB total)
    float* ws       = (float*)d_ws;
    unsigned* cur   = (unsigned*)ws;
    float* sums     = ws + 16;
    float* fpart2   = ws + 32;
    float* inv      = fpart2 + 2 * 16 * 128;
    float* w1       = inv + N2;
    float* w2       = w1 + N2;
    float* u3       = w2 + N2;
    float* rep      = u3 + N2;
    int*   sbins    = (int*)(rep + (size_t)2 * HQ * BB * HN);
    int*   dbins    = sbins + (size_t)2 * 4 * CAP;

    const dim3 sgrid(BB, HQ, 2);     // 512 blocks x 1024 thr, 2/CU, 32 waves/CU
    const size_t lds_bytes = (size_t)HN * sizeof(float);  // 50 KB
    const int gQ = (N2 / 4 + 63) / 64;   // 391 reduce blocks
    const float u0 = 1.0f / (float)N;
    const int zc4 = (16 + 16 + 2 * 16 * 128) / 4;   // cur+sums+fpart2

    zero_kernel<<<16, 256, 0, stream>>>(ws, zc4);

    bin_kernel<<<dim3(256, 2), 512, 0, stream>>>(src_p, dst_p, src_s, dst_s,
                                                 sbins, dbins, cur, E, HN);

    // deg from dst-binned edges (+1 each), then inv = 1/max(deg,1)
    scan_binned<<<sgrid, 1024, lds_bytes, stream>>>(dbins, cur + 8, nullptr,
                                                    rep, N, HN, 1.0f);
    reduce_inv<<<gQ, 256, 0, stream>>>(rep, inv, N, HN);

    scan_binned<<<sgrid, 1024, lds_bytes, stream>>>(sbins, cur, inv,
                                                    rep, N, HN, u0);
    reduce_u<<<gQ, 256, 0, stream>>>(rep, inv, nullptr, w1, sums, 0, N, HN);

    scan_binned<<<sgrid, 1024, lds_bytes, stream>>>(sbins, cur, w1,
                                                    rep, N, HN, 1.0f);
    reduce_u<<<gQ, 256, 0, stream>>>(rep, inv, nullptr, w2, sums, 1, N, HN);

    scan_binned<<<sgrid, 1024, lds_bytes, stream>>>(sbins, cur, w2,
                                                    rep, N, HN, 1.0f);
    reduce_u<<<gQ, 256, 0, stream>>>(rep, inv, u3, nullptr, nullptr, 0, N, HN);

    featsum_kernel<<<dim3(FB, 2), 256, 0, stream>>>(feat_p, feat_s, u3, fpart2, N, rpb);

    final_kernel<<<1, 512, 0, stream>>>(fpart2, sums, W0, b0, W1, b1, W2, b2,
                                        Wr, br, Wm1, bm1, Wm2, bm2, out);
}

// Round 3
// 305.455 us; speedup vs baseline: 1.4252x; 1.1520x over previous
//
#include <hip/hip_runtime.h>
#include <math.h>

#define D 128
#define NPB 128      // nodes per bucket (power of 2: shift 7, mask 127)
#define BCAP 5120    // per-bucket edge capacity (mean 4096, +16 sigma), mult of 4
#define NBB 128      // bin blocks per graph

// ---------------------------------------------------------------------------
// Collapsed linear GCN (math unchanged):
//   u0 = 1/N,  u_{k+1}[s] = sum_{e: src_e=s} inv_deg[dst_e] * u_k[dst_e]
//   mean(h3) = r@W0W1W2 + s2*(b0@W1W2) + s1*(b1@W2) + b2,  r = u3^T feat
// MEASURED LESSONS:
//   R9-R11: kernel boundaries are the only cheap cross-XCD coherence.
//   R13: scattered global fp32 atomics = 171us for 3.2M adds. NEVER
//        scatter-atomic at E scale; atomics on FEW addresses are fine.
//   R14: ballot-ranking binning = 65us VALU-bound (80 instr/edge); traffic
//        prediction was exact (38MB) -> binning must be counting-sort style.
// R15 (this round): fine binning (391 buckets x 128 nodes) so scan blocks
// own their nodes: rep buffer (51.2MB/pass round-trip) + all reduce kernels
// eliminated; bin via 2-phase LDS-histogram counting sort (~6 ops/edge).
// ---------------------------------------------------------------------------

__global__ __launch_bounds__(256) void zero_kernel(float* __restrict__ buf, int n4) {
    float4* b4 = (float4*)buf;
    const float4 z = make_float4(0.f, 0.f, 0.f, 0.f);
    const int stride = gridDim.x * 256;
    for (int i = blockIdx.x * 256 + threadIdx.x; i < n4; i += stride) b4[i] = z;
}

// Two-phase counting-sort binning. Phase 1: LDS histogram of this block's
// edge chunk (src buckets + dst buckets). Reservation: ~nbkt global atomics
// per block on 4*nbkt addresses. Phase 2: re-read chunk, LDS-cursor rank,
// scatter payload. src payload: (src&127)<<17 | dst. dst payload: dst&127.
__global__ __launch_bounds__(512) void bin_kernel(
        const int* __restrict__ src_p, const int* __restrict__ dst_p,
        const int* __restrict__ src_s, const int* __restrict__ dst_s,
        int* __restrict__ sbins, unsigned char* __restrict__ dbins,
        unsigned* __restrict__ cur, int E, int nbkt) {
    const int g = blockIdx.y;
    const int* src = g ? src_s : src_p;
    const int* dst = g ? dst_s : dst_p;
    int* sb = sbins + (size_t)g * nbkt * BCAP;
    unsigned char* db = dbins + (size_t)g * nbkt * BCAP;
    unsigned* scur = cur + g * nbkt;
    unsigned* dcur = cur + 2 * nbkt + g * nbkt;

    __shared__ unsigned shist[512], dhist[512];
    __shared__ unsigned sbase[512], dbase[512];
    const int tid = threadIdx.x;
    for (int i = tid; i < nbkt; i += 512) { shist[i] = 0u; dhist[i] = 0u; }
    __syncthreads();

    const int per = ((E + NBB - 1) / NBB + 3) & ~3;
    const int e0 = blockIdx.x * per;
    const int e1 = min(e0 + per, E);
    const int efull = e0 + ((e1 - e0) & ~3);

    // phase 1: count
    for (int e = e0 + tid * 4; e + 4 <= e1; e += 512 * 4) {
        int4 s4 = *(const int4*)(src + e);
        int4 d4 = *(const int4*)(dst + e);
        atomicAdd(&shist[s4.x >> 7], 1u);
        atomicAdd(&shist[s4.y >> 7], 1u);
        atomicAdd(&shist[s4.z >> 7], 1u);
        atomicAdd(&shist[s4.w >> 7], 1u);
        atomicAdd(&dhist[d4.x >> 7], 1u);
        atomicAdd(&dhist[d4.y >> 7], 1u);
        atomicAdd(&dhist[d4.z >> 7], 1u);
        atomicAdd(&dhist[d4.w >> 7], 1u);
    }
    for (int e = efull + tid; e < e1; e += 512) {
        atomicAdd(&shist[src[e] >> 7], 1u);
        atomicAdd(&dhist[dst[e] >> 7], 1u);
    }
    __syncthreads();

    // reserve global ranges for this block (atomics on few addresses: OK)
    for (int i = tid; i < nbkt; i += 512) {
        unsigned c = shist[i];
        sbase[i] = c ? atomicAdd(&scur[i], c) : 0u;
        c = dhist[i];
        dbase[i] = c ? atomicAdd(&dcur[i], c) : 0u;
    }
    __syncthreads();

    // phase 2: scatter (sbase/dbase double as running cursors)
    for (int e = e0 + tid * 4; e + 4 <= e1; e += 512 * 4) {
        int4 s4 = *(const int4*)(src + e);
        int4 d4 = *(const int4*)(dst + e);
        int sv[4] = {s4.x, s4.y, s4.z, s4.w};
        int dv[4] = {d4.x, d4.y, d4.z, d4.w};
        #pragma unroll
        for (int k = 0; k < 4; ++k) {
            int q = sv[k] >> 7;
            unsigned p = atomicAdd(&sbase[q], 1u);
            if (p < (unsigned)BCAP)
                sb[(size_t)q * BCAP + p] = ((sv[k] & 127) << 17) | dv[k];
            int qd = dv[k] >> 7;
            unsigned pd = atomicAdd(&dbase[qd], 1u);
            if (pd < (unsigned)BCAP)
                db[(size_t)qd * BCAP + pd] = (unsigned char)(dv[k] & 127);
        }
    }
    for (int e = efull + tid; e < e1; e += 512) {
        int s = src[e], d2 = dst[e];
        int q = s >> 7;
        unsigned p = atomicAdd(&sbase[q], 1u);
        if (p < (unsigned)BCAP) sb[(size_t)q * BCAP + p] = ((s & 127) << 17) | d2;
        int qd = d2 >> 7;
        unsigned pd = atomicAdd(&dbase[qd], 1u);
        if (pd < (unsigned)BCAP) db[(size_t)qd * BCAP + pd] = (unsigned char)(d2 & 127);
    }
}

// deg + inv fused: block (q,g) counts its bucket's dst hits, writes inv.
__global__ __launch_bounds__(256) void deg_scan(
        const unsigned char* __restrict__ dbins, const unsigned* __restrict__ cur,
        float* __restrict__ inv, int N, int nbkt) {
    const int q = blockIdx.x, g = blockIdx.y;
    const unsigned char* bin = dbins + (size_t)(g * nbkt + q) * BCAP;
    const int cnt = min((int)cur[2 * nbkt + g * nbkt + q], BCAP);
    const int tid = threadIdx.x;
    __shared__ float bl[NPB];
    if (tid < NPB) bl[tid] = 0.f;
    __syncthreads();
    const uchar4* b4 = (const uchar4*)bin;
    const int nq = cnt >> 2;
    for (int i = tid; i < nq; i += 256) {
        uchar4 v = b4[i];
        atomicAdd(&bl[v.x], 1.f);
        atomicAdd(&bl[v.y], 1.f);
        atomicAdd(&bl[v.z], 1.f);
        atomicAdd(&bl[v.w], 1.f);
    }
    for (int e = (nq << 2) + tid; e < cnt; e += 256) atomicAdd(&bl[bin[e]], 1.f);
    __syncthreads();
    if (tid < NPB) {
        int node = q * NPB + tid;
        if (node < N) inv[(size_t)g * N + node] = 1.0f / fmaxf(bl[tid], 1.0f);
    }
}

// prop pass: block (q,g) owns nodes [q*128, q*128+128). Gathers w[dst],
// LDS-accumulates at src_local, then directly emits w_next = u*inv (and/or
// u3), plus one atomic partial of sum(u) per block.
__global__ __launch_bounds__(256) void prop_scan(
        const int* __restrict__ sbins, const unsigned* __restrict__ cur,
        const float* __restrict__ w, const float* __restrict__ inv,
        float* __restrict__ out_w, float* __restrict__ out_u,
        float* __restrict__ sums, int s_idx, int N, int nbkt, float scale) {
    const int q = blockIdx.x, g = blockIdx.y;
    const int* bin = sbins + (size_t)(g * nbkt + q) * BCAP;
    const int cnt = min((int)cur[g * nbkt + q], BCAP);
    const float* wg = w + (size_t)g * N;
    const int tid = threadIdx.x;
    __shared__ float bl[NPB];
    __shared__ float red[256];
    if (tid < NPB) bl[tid] = 0.f;
    __syncthreads();
    const int4* b4 = (const int4*)bin;
    const int nq = cnt >> 2;
    for (int i = tid; i < nq; i += 256) {
        int4 v = b4[i];
        float a = wg[v.x & 0x1FFFF];
        float b = wg[v.y & 0x1FFFF];
        float c = wg[v.z & 0x1FFFF];
        float d2 = wg[v.w & 0x1FFFF];
        atomicAdd(&bl[((unsigned)v.x) >> 17], a);
        atomicAdd(&bl[((unsigned)v.y) >> 17], b);
        atomicAdd(&bl[((unsigned)v.z) >> 17], c);
        atomicAdd(&bl[((unsigned)v.w) >> 17], d2);
    }
    for (int e = (nq << 2) + tid; e < cnt; e += 256) {
        int v = bin[e];
        atomicAdd(&bl[((unsigned)v) >> 17], wg[v & 0x1FFFF]);
    }
    __syncthreads();
    float u = 0.f;
    if (tid < NPB) {
        int node = q * NPB + tid;
        if (node < N) {
            u = bl[tid] * scale;
            size_t off = (size_t)g * N + node;
            if (out_w) out_w[off] = u * inv[off];
            if (out_u) out_u[off] = u;
        }
    }
    if (sums) {
        red[tid] = u;
        __syncthreads();
        for (int st = 128; st > 0; st >>= 1) {
            if (tid < st) red[tid] += red[tid + st];
            __syncthreads();
        }
        if (tid == 0 && red[0] != 0.f) atomicAdd(&sums[g * 2 + s_idx], red[0]);
    }
}

// featsum: per-block partial of u3^T feat, atomically accumulated into
// fpart2[g][blockIdx.x & 15][c]  (fpart2 pre-zeroed by zero_kernel).
__global__ __launch_bounds__(256) void featsum_kernel(
        const float* __restrict__ feat_p, const float* __restrict__ feat_s,
        const float* __restrict__ u3, float* __restrict__ fpart2,
        int N, int rpb) {
    const int g = blockIdx.y;
    const float* feat = g ? feat_s : feat_p;
    const float* u = u3 + (size_t)g * N;
    const int col4 = threadIdx.x & 31;
    const int rgrp = threadIdx.x >> 5;   // 0..7
    const int r0 = blockIdx.x * rpb;
    const int r1 = min(r0 + rpb, N);

    const float4* f4 = (const float4*)feat;
    float4 acc = make_float4(0.f, 0.f, 0.f, 0.f);
    for (int n = r0 + rgrp * 4; n + 3 < r1; n += 32) {
        float4 uu = *(const float4*)(u + n);
        float4 v0 = f4[(size_t)n * 32 + col4];
        float4 v1 = f4[(size_t)(n + 1) * 32 + col4];
        float4 v2 = f4[(size_t)(n + 2) * 32 + col4];
        float4 v3 = f4[(size_t)(n + 3) * 32 + col4];
        acc.x += uu.x * v0.x + uu.y * v1.x + uu.z * v2.x + uu.w * v3.x;
        acc.y += uu.x * v0.y + uu.y * v1.y + uu.z * v2.y + uu.w * v3.y;
        acc.z += uu.x * v0.z + uu.y * v1.z + uu.z * v2.z + uu.w * v3.z;
        acc.w += uu.x * v0.w + uu.y * v1.w + uu.z * v2.w + uu.w * v3.w;
    }
    __shared__ float4 smem[256];
    smem[threadIdx.x] = acc;
    __syncthreads();
    if (rgrp == 0) {
        float4 t = smem[col4];
        #pragma unroll
        for (int k = 1; k < 8; k++) {
            float4 o = smem[k * 32 + col4];
            t.x += o.x; t.y += o.y; t.z += o.z; t.w += o.w;
        }
        float* dst = fpart2 + ((size_t)g * 16 + (blockIdx.x & 15)) * 128 + col4 * 4;
        atomicAdd(dst + 0, t.x);
        atomicAdd(dst + 1, t.y);
        atomicAdd(dst + 2, t.z);
        atomicAdd(dst + 3, t.w);
    }
}

// 512 threads: split-K matvecs. j = tid&127, h = tid>>7.
__global__ __launch_bounds__(512) void final_kernel(
        const float* __restrict__ fpart2,
        const float* __restrict__ sums,
        const float* __restrict__ W0, const float* __restrict__ b0,
        const float* __restrict__ W1, const float* __restrict__ b1,
        const float* __restrict__ W2, const float* __restrict__ b2,
        const float* __restrict__ Wr, const float* __restrict__ br,
        const float* __restrict__ Wm1, const float* __restrict__ bm1,
        const float* __restrict__ Wm2, const float* __restrict__ bm2,
        float* __restrict__ out) {
    __shared__ float x[128];
    __shared__ float part[4][128];
    __shared__ float rvec[256];
    __shared__ float Avec[128], Bvec[128];
    __shared__ float gv[256];
    const int tid = threadIdx.x;
    const int j = tid & 127;
    const int h = tid >> 7;

    auto mv128 = [&](const float* __restrict__ W, float* __restrict__ buf) {
        float p = 0.f;
        const float* Wp = W + (size_t)(h * 32) * 128 + j;
        #pragma unroll
        for (int i = 0; i < 32; ++i) p += buf[h * 32 + i] * Wp[(size_t)i * 128];
        part[h][j] = p;
        __syncthreads();
        if (h == 0) buf[j] = part[0][j] + part[1][j] + part[2][j] + part[3][j];
        __syncthreads();
    };

    if (tid < 256) {
        int g = tid >> 7;
        const float* fp = fpart2 + (size_t)g * 2048 + (tid & 127);
        float rv = 0.f;
        #pragma unroll
        for (int b = 0; b < 16; ++b) rv += fp[(size_t)b * 128];
        rvec[tid] = rv;
    }
    __syncthreads();

    if (tid < 128) x[tid] = b0[tid];
    __syncthreads();
    mv128(W1, x);
    mv128(W2, x);
    if (tid < 128) Avec[tid] = x[tid];
    __syncthreads();
    if (tid < 128) x[tid] = b1[tid];
    __syncthreads();
    mv128(W2, x);
    if (tid < 128) Bvec[tid] = x[tid];
    __syncthreads();

    for (int g = 0; g < 2; ++g) {
        const float s1 = sums[g * 2 + 0];
        const float s2 = sums[g * 2 + 1];
        if (tid < 128) x[tid] = rvec[g * 128 + tid];
        __syncthreads();
        mv128(W0, x);
        mv128(W1, x);
        mv128(W2, x);
        if (tid < 128) x[tid] += s2 * Avec[tid] + s1 * Bvec[tid] + b2[tid];
        __syncthreads();
        mv128(Wr, x);
        if (tid < 128) gv[g * 128 + tid] = 1.0f / (1.0f + expf(-(x[tid] + br[tid])));
        __syncthreads();
    }

    {
        float p = 0.f;
        const float* Wp = Wm1 + (size_t)(h * 64) * 128 + j;
        #pragma unroll
        for (int i = 0; i < 64; ++i) p += gv[h * 64 + i] * Wp[(size_t)i * 128];
        part[h][j] = p;
        __syncthreads();
        if (h == 0)
            part[0][j] = (part[0][j] + part[1][j] + part[2][j] + part[3][j] + bm1[j]) * Wm2[j];
        __syncthreads();
        if (tid < 64) part[0][tid] += part[0][tid + 64];
        __syncthreads();
        if (tid < 32) part[0][tid] += part[0][tid + 32];
        __syncthreads();
        if (tid < 16) part[0][tid] += part[0][tid + 16];
        __syncthreads();
        if (tid < 8) part[0][tid] += part[0][tid + 8];
        __syncthreads();
        if (tid < 4) part[0][tid] += part[0][tid + 4];
        __syncthreads();
        if (tid < 2) part[0][tid] += part[0][tid + 2];
        __syncthreads();
        if (tid == 0) out[0] = 1.0f / (1.0f + expf(-(part[0][0] + part[0][1] + bm2[0])));
    }
}

extern "C" void kernel_launch(void* const* d_in, const int* in_sizes, int n_in,
                              void* d_out, int out_size, void* d_ws, size_t ws_size,
                              hipStream_t stream) {
    const float* feat_p = (const float*)d_in[0];
    const int*   src_p  = (const int*)d_in[1];
    const int*   dst_p  = (const int*)d_in[2];
    const float* feat_s = (const float*)d_in[3];
    const int*   src_s  = (const int*)d_in[4];
    const int*   dst_s  = (const int*)d_in[5];
    const float* W0 = (const float*)d_in[6];
    const float* b0 = (const float*)d_in[7];
    const float* W1 = (const float*)d_in[8];
    const float* b1 = (const float*)d_in[9];
    const float* W2 = (const float*)d_in[10];
    const float* b2 = (const float*)d_in[11];
    const float* Wr = (const float*)d_in[12];
    const float* br = (const float*)d_in[13];
    const float* Wm1 = (const float*)d_in[14];
    const float* bm1 = (const float*)d_in[15];
    const float* Wm2 = (const float*)d_in[16];
    const float* bm2 = (const float*)d_in[17];
    float* out = (float*)d_out;

    const int N = in_sizes[0] / D;   // 50000
    const int E = in_sizes[1];       // 1600000
    const int N2 = 2 * N;
    const int nbkt = (N + NPB - 1) / NPB;   // 391
    const int FB = 256;              // featsum blocks per graph
    const int rpb = (((N + FB - 1) / FB) + 3) & ~3;   // 196

    // ws (floats): cur[4*nbkt u32] | sums[16] | fpart2[2*16*128] | inv[2N] |
    //              w1[2N] | w2[2N] | u3[2N] | sbins[2*nbkt*BCAP int] |
    //              dbins[2*nbkt*BCAP uchar]   (~22 MB total)
    float* ws       = (float*)d_ws;
    unsigned* cur   = (unsigned*)ws;
    const int curN  = 4 * nbkt;            // 1564 (mult of 4)
    float* sums     = ws + curN;
    float* fpart2   = sums + 16;
    float* inv      = fpart2 + 2 * 16 * 128;
    float* w1       = inv + N2;
    float* w2       = w1 + N2;
    float* u3       = w2 + N2;
    int*   sbins    = (int*)(u3 + N2);
    unsigned char* dbins = (unsigned char*)(sbins + (size_t)2 * nbkt * BCAP);

    const float u0 = 1.0f / (float)N;
    const int zc4 = (curN + 16 + 2 * 16 * 128) / 4;   // cur+sums+fpart2

    zero_kernel<<<16, 256, 0, stream>>>(ws, zc4);

    bin_kernel<<<dim3(NBB, 2), 512, 0, stream>>>(src_p, dst_p, src_s, dst_s,
                                                 sbins, dbins, cur, E, nbkt);

    deg_scan<<<dim3(nbkt, 2), 256, 0, stream>>>(dbins, cur, inv, N, nbkt);

    prop_scan<<<dim3(nbkt, 2), 256, 0, stream>>>(sbins, cur, inv, inv,
                                                 w1, nullptr, sums, 0,
                                                 N, nbkt, u0);
    prop_scan<<<dim3(nbkt, 2), 256, 0, stream>>>(sbins, cur, w1, inv,
                                                 w2, nullptr, sums, 1,
                                                 N, nbkt, 1.0f);
    prop_scan<<<dim3(nbkt, 2), 256, 0, stream>>>(sbins, cur, w2, inv,
                                                 nullptr, u3, nullptr, 0,
                                                 N, nbkt, 1.0f);

    featsum_kernel<<<dim3(FB, 2), 256, 0, stream>>>(feat_p, feat_s, u3, fpart2, N, rpb);

    final_kernel<<<1, 512, 0, stream>>>(fpart2, sums, W0, b0, W1, b1, W2, b2,
                                        Wr, br, Wm1, bm1, Wm2, bm2, out);
}

// Round 4
// 279.440 us; speedup vs baseline: 1.5578x; 1.0931x over previous
//
#include <hip/hip_runtime.h>
#include <math.h>

#define D 128
#define BSH 9        // bucket shift: 512 nodes/bucket
#define NPB 512      // nodes per bucket
#define BCAP 17920   // per-bucket edge cap: mean 16384 + 12 sigma, mult of 4
#define STCAP 6252   // edges staged per bin block (mult of 4); NBB = ceil(E/STCAP)

// ---------------------------------------------------------------------------
// Collapsed linear GCN (math unchanged):
//   u0 = 1/N,  u_{k+1}[s] = sum_{e: src_e=s} inv_deg[dst_e] * u_k[dst_e]
//   mean(h3) = r@W0W1W2 + s2*(b0@W1W2) + s1*(b1@W2) + b2,  r = u3^T feat
// MEASURED LESSONS:
//   R9-R11: kernel boundaries are the only cheap cross-XCD coherence.
//   R13: scattered global fp32 atomics = 171us for 3.2M adds. NEVER
//        scatter-atomic at E scale; atomics on FEW addresses are fine.
//   R14: ballot-ranking binning = 65us VALU-bound (80 instr/edge).
//   R15: direct 4B scatter to 391x2 buckets = 7x WRITE amplification
//        (108MB vs 16MB payload, partial lines bounce across XCD L2s);
//        also NPB=128 LDS bins concentrate atomic contention.
// R16 (this round):
//   - bin: LDS-staged counting sort (histogram whole 6252-edge chunk,
//     shfl exclusive-scan, stage payloads bucket-ordered in LDS, copy out
//     256B+ contiguous runs per bucket) -> full-line writes.
//   - scans: 512-node buckets + 8 per-wave LDS replica bins -> ~16x less
//     same-address atomic serialization; merge replicas at the end.
// ---------------------------------------------------------------------------

__global__ __launch_bounds__(256) void zero_kernel(float* __restrict__ buf, int n4) {
    float4* b4 = (float4*)buf;
    const float4 z = make_float4(0.f, 0.f, 0.f, 0.f);
    const int stride = gridDim.x * 256;
    for (int i = blockIdx.x * 256 + threadIdx.x; i < n4; i += stride) b4[i] = z;
}

// Counting-sort binning with LDS staging. Payloads:
//   src bucket: (src&511)<<17 | dst   (dst < 2^17)
//   dst bucket: ushort (dst&511)
__global__ __launch_bounds__(512) void bin_kernel(
        const int* __restrict__ src_p, const int* __restrict__ dst_p,
        const int* __restrict__ src_s, const int* __restrict__ dst_s,
        int* __restrict__ sbins, unsigned short* __restrict__ dbins,
        unsigned* __restrict__ cur, int E, int nbkt) {
    const int g = blockIdx.y;
    const int* src = g ? src_s : src_p;
    const int* dst = g ? dst_s : dst_p;
    int* sb = sbins + (size_t)g * nbkt * BCAP;
    unsigned short* db = dbins + (size_t)g * nbkt * BCAP;
    unsigned* scur = cur + g * nbkt;
    unsigned* dcur = cur + 2 * nbkt + g * nbkt;

    __shared__ int sstage[STCAP];
    __shared__ unsigned short dstage[STCAP];
    __shared__ unsigned hist_s[128], hist_d[128];
    __shared__ unsigned offs_s[128], offs_d[128];
    __shared__ unsigned lcur_s[128], lcur_d[128];
    __shared__ unsigned gb_s[128], gb_d[128];

    const int tid = threadIdx.x;
    const int wv = tid >> 6, lane = tid & 63;
    for (int i = tid; i < 128; i += 512) { hist_s[i] = 0u; hist_d[i] = 0u; }
    __syncthreads();

    const int e0 = blockIdx.x * STCAP;
    const int e1 = min(e0 + STCAP, E);
    const int efull = e0 + ((e1 - e0) & ~3);

    // phase 1: histogram the whole chunk
    for (int e = e0 + tid * 4; e + 4 <= e1; e += 512 * 4) {
        int4 s4 = *(const int4*)(src + e);
        int4 d4 = *(const int4*)(dst + e);
        atomicAdd(&hist_s[s4.x >> BSH], 1u);
        atomicAdd(&hist_s[s4.y >> BSH], 1u);
        atomicAdd(&hist_s[s4.z >> BSH], 1u);
        atomicAdd(&hist_s[s4.w >> BSH], 1u);
        atomicAdd(&hist_d[d4.x >> BSH], 1u);
        atomicAdd(&hist_d[d4.y >> BSH], 1u);
        atomicAdd(&hist_d[d4.z >> BSH], 1u);
        atomicAdd(&hist_d[d4.w >> BSH], 1u);
    }
    for (int e = efull + tid; e < e1; e += 512) {
        atomicAdd(&hist_s[src[e] >> BSH], 1u);
        atomicAdd(&hist_d[dst[e] >> BSH], 1u);
    }
    __syncthreads();

    // wave 0/1: exclusive scans; wave 2/3: global range reservation
    if (wv == 0 || wv == 1) {
        const unsigned* h = (wv == 0) ? hist_s : hist_d;
        unsigned* o = (wv == 0) ? offs_s : offs_d;
        unsigned* lc = (wv == 0) ? lcur_s : lcur_d;
        unsigned a = (2 * lane < nbkt) ? h[2 * lane] : 0u;
        unsigned b = (2 * lane + 1 < nbkt) ? h[2 * lane + 1] : 0u;
        unsigned v = a + b;
        for (int d2 = 1; d2 < 64; d2 <<= 1) {
            unsigned t = __shfl_up(v, d2);
            if (lane >= d2) v += t;
        }
        unsigned ex = v - (a + b);
        if (2 * lane < nbkt) { o[2 * lane] = ex; lc[2 * lane] = ex; }
        if (2 * lane + 1 < nbkt) { o[2 * lane + 1] = ex + a; lc[2 * lane + 1] = ex + a; }
    } else if (wv == 2) {
        for (int i = lane; i < nbkt; i += 64) {
            unsigned c = hist_s[i];
            gb_s[i] = c ? atomicAdd(&scur[i], c) : 0u;
        }
    } else if (wv == 3) {
        for (int i = lane; i < nbkt; i += 64) {
            unsigned c = hist_d[i];
            gb_d[i] = c ? atomicAdd(&dcur[i], c) : 0u;
        }
    }
    __syncthreads();

    // phase 2: stage bucket-ordered into LDS (re-read hits L2)
    for (int e = e0 + tid * 4; e + 4 <= e1; e += 512 * 4) {
        int4 s4 = *(const int4*)(src + e);
        int4 d4 = *(const int4*)(dst + e);
        int sv[4] = {s4.x, s4.y, s4.z, s4.w};
        int dv[4] = {d4.x, d4.y, d4.z, d4.w};
        #pragma unroll
        for (int k = 0; k < 4; ++k) {
            unsigned p = atomicAdd(&lcur_s[sv[k] >> BSH], 1u);
            sstage[p] = ((sv[k] & (NPB - 1)) << 17) | dv[k];
            unsigned pd = atomicAdd(&lcur_d[dv[k] >> BSH], 1u);
            dstage[pd] = (unsigned short)(dv[k] & (NPB - 1));
        }
    }
    for (int e = efull + tid; e < e1; e += 512) {
        int s = src[e], d2 = dst[e];
        unsigned p = atomicAdd(&lcur_s[s >> BSH], 1u);
        sstage[p] = ((s & (NPB - 1)) << 17) | d2;
        unsigned pd = atomicAdd(&lcur_d[d2 >> BSH], 1u);
        dstage[pd] = (unsigned short)(d2 & (NPB - 1));
    }
    __syncthreads();

    // copy-out: one wave per bucket, contiguous full-line runs
    for (int b = wv; b < nbkt; b += 8) {
        unsigned cs = hist_s[b], os = offs_s[b], gs = gb_s[b];
        unsigned lim = (gs < (unsigned)BCAP) ? min(cs, (unsigned)BCAP - gs) : 0u;
        int* dp = sb + (size_t)b * BCAP + gs;
        for (unsigned i = lane; i < lim; i += 64) dp[i] = sstage[os + i];
        unsigned cd = hist_d[b], od = offs_d[b], gd = gb_d[b];
        unsigned limd = (gd < (unsigned)BCAP) ? min(cd, (unsigned)BCAP - gd) : 0u;
        unsigned short* ddp = db + (size_t)b * BCAP + gd;
        for (unsigned i = lane; i < limd; i += 64) ddp[i] = dstage[od + i];
    }
}

// deg + inv fused: block (q,g) counts its bucket, 8 per-wave replicas.
__global__ __launch_bounds__(512) void deg_inv(
        const unsigned short* __restrict__ dbins, const unsigned* __restrict__ cur,
        float* __restrict__ inv, int N, int nbkt) {
    const int q = blockIdx.x, g = blockIdx.y;
    const unsigned short* bin = dbins + (size_t)(g * nbkt + q) * BCAP;
    const int cnt = min((int)cur[2 * nbkt + g * nbkt + q], BCAP);
    const int tid = threadIdx.x;
    const int wv = tid >> 6;
    __shared__ float bl[8][NPB];
    for (int i = tid; i < 8 * NPB; i += 512) ((float*)bl)[i] = 0.f;
    __syncthreads();
    float* mybl = bl[wv];
    const ushort4* b4 = (const ushort4*)bin;
    const int n4 = cnt >> 2;
    for (int i = tid; i < n4; i += 512) {
        ushort4 v = b4[i];
        atomicAdd(&mybl[v.x], 1.f);
        atomicAdd(&mybl[v.y], 1.f);
        atomicAdd(&mybl[v.z], 1.f);
        atomicAdd(&mybl[v.w], 1.f);
    }
    for (int e = (n4 << 2) + tid; e < cnt; e += 512) atomicAdd(&mybl[bin[e]], 1.f);
    __syncthreads();
    float t = 0.f;
    #pragma unroll
    for (int r = 0; r < 8; ++r) t += bl[r][tid];
    int node = q * NPB + tid;
    if (node < N) inv[(size_t)g * N + node] = 1.0f / fmaxf(t, 1.0f);
}

// prop pass: block (q,g) owns nodes [q*512, q*512+512). Gathers w[dst],
// accumulates into per-wave replica bins, merges, emits w_next/u3 + sums.
__global__ __launch_bounds__(512) void prop_scan(
        const int* __restrict__ sbins, const unsigned* __restrict__ cur,
        const float* __restrict__ w, const float* __restrict__ inv,
        float* __restrict__ out_w, float* __restrict__ out_u,
        float* __restrict__ sums, int s_idx, int N, int nbkt, float scale) {
    const int q = blockIdx.x, g = blockIdx.y;
    const int* bin = sbins + (size_t)(g * nbkt + q) * BCAP;
    const int cnt = min((int)cur[g * nbkt + q], BCAP);
    const float* wg = w + (size_t)g * N;
    const int tid = threadIdx.x;
    const int wv = tid >> 6;
    __shared__ float bl[8][NPB];
    __shared__ float red[512];
    for (int i = tid; i < 8 * NPB; i += 512) ((float*)bl)[i] = 0.f;
    __syncthreads();
    float* mybl = bl[wv];
    const int4* b4 = (const int4*)bin;
    const int n4 = cnt >> 2;
    for (int i = tid; i < n4; i += 512) {
        int4 v = b4[i];
        float a = wg[v.x & 0x1FFFF];
        float b = wg[v.y & 0x1FFFF];
        float c = wg[v.z & 0x1FFFF];
        float d2 = wg[v.w & 0x1FFFF];
        atomicAdd(&mybl[((unsigned)v.x) >> 17], a);
        atomicAdd(&mybl[((unsigned)v.y) >> 17], b);
        atomicAdd(&mybl[((unsigned)v.z) >> 17], c);
        atomicAdd(&mybl[((unsigned)v.w) >> 17], d2);
    }
    for (int e = (n4 << 2) + tid; e < cnt; e += 512) {
        int v = bin[e];
        atomicAdd(&mybl[((unsigned)v) >> 17], wg[v & 0x1FFFF]);
    }
    __syncthreads();
    float t = 0.f;
    #pragma unroll
    for (int r = 0; r < 8; ++r) t += bl[r][tid];
    const float u = t * scale;
    const int node = q * NPB + tid;
    const bool valid = node < N;
    if (valid) {
        size_t off = (size_t)g * N + node;
        if (out_w) out_w[off] = u * inv[off];
        if (out_u) out_u[off] = u;
    }
    if (sums) {
        red[tid] = valid ? u : 0.f;
        __syncthreads();
        for (int st = 256; st > 0; st >>= 1) {
            if (tid < st) red[tid] += red[tid + st];
            __syncthreads();
        }
        if (tid == 0 && red[0] != 0.f) atomicAdd(&sums[g * 2 + s_idx], red[0]);
    }
}

// featsum: per-block partial of u3^T feat into fpart2[g][blk&15][c].
__global__ __launch_bounds__(256) void featsum_kernel(
        const float* __restrict__ feat_p, const float* __restrict__ feat_s,
        const float* __restrict__ u3, float* __restrict__ fpart2,
        int N, int rpb) {
    const int g = blockIdx.y;
    const float* feat = g ? feat_s : feat_p;
    const float* u = u3 + (size_t)g * N;
    const int col4 = threadIdx.x & 31;
    const int rgrp = threadIdx.x >> 5;   // 0..7
    const int r0 = blockIdx.x * rpb;
    const int r1 = min(r0 + rpb, N);

    const float4* f4 = (const float4*)feat;
    float4 acc = make_float4(0.f, 0.f, 0.f, 0.f);
    for (int n = r0 + rgrp * 4; n + 3 < r1; n += 32) {
        float4 uu = *(const float4*)(u + n);
        float4 v0 = f4[(size_t)n * 32 + col4];
        float4 v1 = f4[(size_t)(n + 1) * 32 + col4];
        float4 v2 = f4[(size_t)(n + 2) * 32 + col4];
        float4 v3 = f4[(size_t)(n + 3) * 32 + col4];
        acc.x += uu.x * v0.x + uu.y * v1.x + uu.z * v2.x + uu.w * v3.x;
        acc.y += uu.x * v0.y + uu.y * v1.y + uu.z * v2.y + uu.w * v3.y;
        acc.z += uu.x * v0.z + uu.y * v1.z + uu.z * v2.z + uu.w * v3.z;
        acc.w += uu.x * v0.w + uu.y * v1.w + uu.z * v2.w + uu.w * v3.w;
    }
    __shared__ float4 smem[256];
    smem[threadIdx.x] = acc;
    __syncthreads();
    if (rgrp == 0) {
        float4 t = smem[col4];
        #pragma unroll
        for (int k = 1; k < 8; k++) {
            float4 o = smem[k * 32 + col4];
            t.x += o.x; t.y += o.y; t.z += o.z; t.w += o.w;
        }
        float* dst = fpart2 + ((size_t)g * 16 + (blockIdx.x & 15)) * 128 + col4 * 4;
        atomicAdd(dst + 0, t.x);
        atomicAdd(dst + 1, t.y);
        atomicAdd(dst + 2, t.z);
        atomicAdd(dst + 3, t.w);
    }
}

// 512 threads: split-K matvecs. j = tid&127, h = tid>>7.
__global__ __launch_bounds__(512) void final_kernel(
        const float* __restrict__ fpart2,
        const float* __restrict__ sums,
        const float* __restrict__ W0, const float* __restrict__ b0,
        const float* __restrict__ W1, const float* __restrict__ b1,
        const float* __restrict__ W2, const float* __restrict__ b2,
        const float* __restrict__ Wr, const float* __restrict__ br,
        const float* __restrict__ Wm1, const float* __restrict__ bm1,
        const float* __restrict__ Wm2, const float* __restrict__ bm2,
        float* __restrict__ out) {
    __shared__ float x[128];
    __shared__ float part[4][128];
    __shared__ float rvec[256];
    __shared__ float Avec[128], Bvec[128];
    __shared__ float gv[256];
    const int tid = threadIdx.x;
    const int j = tid & 127;
    const int h = tid >> 7;

    auto mv128 = [&](const float* __restrict__ W, float* __restrict__ buf) {
        float p = 0.f;
        const float* Wp = W + (size_t)(h * 32) * 128 + j;
        #pragma unroll
        for (int i = 0; i < 32; ++i) p += buf[h * 32 + i] * Wp[(size_t)i * 128];
        part[h][j] = p;
        __syncthreads();
        if (h == 0) buf[j] = part[0][j] + part[1][j] + part[2][j] + part[3][j];
        __syncthreads();
    };

    if (tid < 256) {
        int g = tid >> 7;
        const float* fp = fpart2 + (size_t)g * 2048 + (tid & 127);
        float rv = 0.f;
        #pragma unroll
        for (int b = 0; b < 16; ++b) rv += fp[(size_t)b * 128];
        rvec[tid] = rv;
    }
    __syncthreads();

    if (tid < 128) x[tid] = b0[tid];
    __syncthreads();
    mv128(W1, x);
    mv128(W2, x);
    if (tid < 128) Avec[tid] = x[tid];
    __syncthreads();
    if (tid < 128) x[tid] = b1[tid];
    __syncthreads();
    mv128(W2, x);
    if (tid < 128) Bvec[tid] = x[tid];
    __syncthreads();

    for (int g = 0; g < 2; ++g) {
        const float s1 = sums[g * 2 + 0];
        const float s2 = sums[g * 2 + 1];
        if (tid < 128) x[tid] = rvec[g * 128 + tid];
        __syncthreads();
        mv128(W0, x);
        mv128(W1, x);
        mv128(W2, x);
        if (tid < 128) x[tid] += s2 * Avec[tid] + s1 * Bvec[tid] + b2[tid];
        __syncthreads();
        mv128(Wr, x);
        if (tid < 128) gv[g * 128 + tid] = 1.0f / (1.0f + expf(-(x[tid] + br[tid])));
        __syncthreads();
    }

    {
        float p = 0.f;
        const float* Wp = Wm1 + (size_t)(h * 64) * 128 + j;
        #pragma unroll
        for (int i = 0; i < 64; ++i) p += gv[h * 64 + i] * Wp[(size_t)i * 128];
        part[h][j] = p;
        __syncthreads();
        if (h == 0)
            part[0][j] = (part[0][j] + part[1][j] + part[2][j] + part[3][j] + bm1[j]) * Wm2[j];
        __syncthreads();
        if (tid < 64) part[0][tid] += part[0][tid + 64];
        __syncthreads();
        if (tid < 32) part[0][tid] += part[0][tid + 32];
        __syncthreads();
        if (tid < 16) part[0][tid] += part[0][tid + 16];
        __syncthreads();
        if (tid < 8) part[0][tid] += part[0][tid + 8];
        __syncthreads();
        if (tid < 4) part[0][tid] += part[0][tid + 4];
        __syncthreads();
        if (tid < 2) part[0][tid] += part[0][tid + 2];
        __syncthreads();
        if (tid == 0) out[0] = 1.0f / (1.0f + expf(-(part[0][0] + part[0][1] + bm2[0])));
    }
}

extern "C" void kernel_launch(void* const* d_in, const int* in_sizes, int n_in,
                              void* d_out, int out_size, void* d_ws, size_t ws_size,
                              hipStream_t stream) {
    const float* feat_p = (const float*)d_in[0];
    const int*   src_p  = (const int*)d_in[1];
    const int*   dst_p  = (const int*)d_in[2];
    const float* feat_s = (const float*)d_in[3];
    const int*   src_s  = (const int*)d_in[4];
    const int*   dst_s  = (const int*)d_in[5];
    const float* W0 = (const float*)d_in[6];
    const float* b0 = (const float*)d_in[7];
    const float* W1 = (const float*)d_in[8];
    const float* b1 = (const float*)d_in[9];
    const float* W2 = (const float*)d_in[10];
    const float* b2 = (const float*)d_in[11];
    const float* Wr = (const float*)d_in[12];
    const float* br = (const float*)d_in[13];
    const float* Wm1 = (const float*)d_in[14];
    const float* bm1 = (const float*)d_in[15];
    const float* Wm2 = (const float*)d_in[16];
    const float* bm2 = (const float*)d_in[17];
    float* out = (float*)d_out;

    const int N = in_sizes[0] / D;   // 50000
    const int E = in_sizes[1];       // 1600000
    const int N2 = 2 * N;
    const int nbkt = (N + NPB - 1) >> BSH;        // 98
    const int NBB = (E + STCAP - 1) / STCAP;      // 256
    const int FB = 256;              // featsum blocks per graph
    const int rpb = (((N + FB - 1) / FB) + 3) & ~3;   // 196

    // ws (floats): cur[4*nbkt u32, pad4] | sums[16] | fpart2[2*16*128] |
    //              inv[2N] | w1[2N] | w2[2N] | u3[2N] |
    //              sbins[2*nbkt*BCAP int] | dbins[2*nbkt*BCAP ushort]  (~23 MB)
    float* ws       = (float*)d_ws;
    unsigned* cur   = (unsigned*)ws;
    const int curN  = (4 * nbkt + 3) & ~3;        // 392
    float* sums     = ws + curN;
    float* fpart2   = sums + 16;
    float* inv      = fpart2 + 2 * 16 * 128;
    float* w1       = inv + N2;
    float* w2       = w1 + N2;
    float* u3       = w2 + N2;
    int*   sbins    = (int*)(u3 + N2);
    unsigned short* dbins = (unsigned short*)(sbins + (size_t)2 * nbkt * BCAP);

    const float u0 = 1.0f / (float)N;
    const int zc4 = (curN + 16 + 2 * 16 * 128) / 4;   // cur+sums+fpart2

    zero_kernel<<<16, 256, 0, stream>>>(ws, zc4);

    bin_kernel<<<dim3(NBB, 2), 512, 0, stream>>>(src_p, dst_p, src_s, dst_s,
                                                 sbins, dbins, cur, E, nbkt);

    deg_inv<<<dim3(nbkt, 2), 512, 0, stream>>>(dbins, cur, inv, N, nbkt);

    prop_scan<<<dim3(nbkt, 2), 512, 0, stream>>>(sbins, cur, inv, inv,
                                                 w1, nullptr, sums, 0,
                                                 N, nbkt, u0);
    prop_scan<<<dim3(nbkt, 2), 512, 0, stream>>>(sbins, cur, w1, inv,
                                                 w2, nullptr, sums, 1,
                                                 N, nbkt, 1.0f);
    prop_scan<<<dim3(nbkt, 2), 512, 0, stream>>>(sbins, cur, w2, inv,
                                                 nullptr, u3, nullptr, 0,
                                                 N, nbkt, 1.0f);

    featsum_kernel<<<dim3(FB, 2), 256, 0, stream>>>(feat_p, feat_s, u3, fpart2, N, rpb);

    final_kernel<<<1, 512, 0, stream>>>(fpart2, sums, W0, b0, W1, b1, W2, b2,
                                        Wr, br, Wm1, bm1, Wm2, bm2, out);
}